// Round 1
// 828.359 us; speedup vs baseline: 1.2058x; 1.2058x over previous
//
#include <hip/hip_runtime.h>

typedef __attribute__((ext_vector_type(4))) float f4v;
typedef __attribute__((ext_vector_type(8))) short s8v;

#define YPITCH 72   // shorts; 144 B rows -> (mn+quad)&7 16B-slot walk, 2-way = free
#define NB 4        // batches per block
#define MROWS 68    // real M rows (4 batches x 17 joints)
#define MT 5        // padded M-tiles (80 rows)

static __device__ __forceinline__ short f2bf(float f) {
    unsigned u = __builtin_bit_cast(unsigned, f);
    unsigned r = (u + 0x7FFFu + ((u >> 16) & 1u)) >> 16;  // RNE
    return (short)r;
}

#define GLOAD_LDS16(g, l) __builtin_amdgcn_global_load_lds( \
    (const __attribute__((address_space(1))) unsigned*)(g), \
    (__attribute__((address_space(3))) unsigned*)(l), 16, 0, 0)

// W[3][256][256] (k,f,o) fp32  ->  Wt[3][256][256] (k,o,f) bf16, via LDS tile transpose
__global__ void wt_transpose_kernel(const float* __restrict__ W, short* __restrict__ Wt) {
    __shared__ short t[64][65];
    int k  = blockIdx.x >> 4;
    int r  = blockIdx.x & 15;
    int f0 = (r >> 2) << 6;
    int o0 = (r & 3) << 6;
    const float* Wk  = W  + k * 65536;
    short*       Wtk = Wt + k * 65536;
    #pragma unroll
    for (int e = 0; e < 16; e++) {
        int idx = e * 256 + threadIdx.x;
        int f = idx >> 6, o = idx & 63;
        t[f][o] = f2bf(Wk[(f0 + f) * 256 + o0 + o]);
    }
    __syncthreads();
    #pragma unroll
    for (int e = 0; e < 16; e++) {
        int idx = e * 256 + threadIdx.x;
        int o = idx >> 6, f = idx & 63;
        Wtk[(o0 + o) * 256 + f0 + f] = t[f][o];
    }
}

// Full-N blocks: 4 batches (M=68 rows, padded to 80), N=256, x read once.
// Ws staged via global_load_lds (linear dest + src-XOR-preswizzle, XOR on read).
// Aggregation fp32 in regs -> v_cvt_pk_bf16_f32 -> Ys -> MFMA.
__global__ __launch_bounds__(256, 3) void gconv_kernel(
        const float* __restrict__ x, const short* __restrict__ Wt,
        const float* __restrict__ adj, const float* __restrict__ bias,
        float* __restrict__ out) {
    __shared__ __align__(16) short Ys[80 * YPITCH];   // 11520 B
    __shared__ __align__(16) short Ws[256 * 64];      // 32768 B, XOR-swizzled slots

    const int tid  = threadIdx.x;
    const int wave = tid >> 6;        // 0..3: batch for agg, N-quarter for MFMA
    const int lane = tid & 63;
    const int mn   = lane & 15;
    const int quad = lane >> 4;
    const int bb   = wave;            // local batch 0..3
    const int f    = lane;            // column within 64-wide fc chunk

    const float* xg = x   + (size_t)blockIdx.x * (NB * 17 * 256);
    float*       og = out + (size_t)blockIdx.x * (NB * 17 * 256);

    // zero pad rows 68..79 once (never rewritten; covered by first barrier)
    for (int idx = tid; idx < (12 * YPITCH) / 2; idx += 256)
        ((int*)(Ys + MROWS * YPITCH))[idx] = 0;

    f4v acc[MT][4];
    #pragma unroll
    for (int nt = 0; nt < 4; nt++) {
        float bv = bias[wave * 64 + nt * 16 + mn];
        #pragma unroll
        for (int mt = 0; mt < MT; mt++) acc[mt][nt] = (f4v){bv, bv, bv, bv};
    }

    // source-side swizzle offset (shorts): slot' = slot ^ (c&7); here c&7 == lane>>3
    const int subsw = ((lane & 7) ^ (lane >> 3)) << 3;

    for (int fc0 = 0; fc0 < 256; fc0 += 64) {
        float xq[17];
        #pragma unroll
        for (int j = 0; j < 17; j++)
            xq[j] = xg[(bb * 17 + j) * 256 + fc0 + f];

        #pragma unroll
        for (int k = 0; k < 3; k++) {
            // ---- stage Ws[c][0..63] (c = output col) via global_load_lds, issued first ----
            const short* Wtk = Wt + k * 65536;
            #pragma unroll
            for (int e = 0; e < 8; e++) {
                int c = (wave * 8 + e) * 8 + (lane >> 3);
                GLOAD_LDS16(Wtk + c * 256 + fc0 + subsw,
                            (char*)Ws + (wave * 8 + e) * 1024);
            }

            // ---- aggregation: Y_k rows for 17 joints of batch bb, fp32 regs ----
            float y[17];
            if (k == 0) {
                #pragma unroll
                for (int i = 0; i < 17; i++) y[i] = adj[i * 17 + i] * xq[i];
            } else if (k == 1) {
                #pragma unroll
                for (int i = 0; i < 17; i++) {
                    float a = 0.f;
                    #pragma unroll
                    for (int j = i + 1; j < 17; j++) a += adj[i * 17 + j] * xq[j];
                    y[i] = a;
                }
            } else {
                #pragma unroll
                for (int i = 0; i < 17; i++) {
                    float a = 0.f;
                    #pragma unroll
                    for (int j = 0; j < i; j++) a += adj[i * 17 + j] * xq[j];
                    y[i] = a;
                }
            }

            // ---- fp32 -> bf16 via HW cvt_pk, write column f of rows bb*17+i ----
            short* yrow = Ys + (bb * 17) * YPITCH + f;
            #pragma unroll
            for (int p = 0; p < 8; p++) {
                unsigned r;
                asm("v_cvt_pk_bf16_f32 %0, %1, %2" : "=v"(r) : "v"(y[2 * p]), "v"(y[2 * p + 1]));
                yrow[(2 * p) * YPITCH]     = (short)(r & 0xffffu);
                yrow[(2 * p + 1) * YPITCH] = (short)(r >> 16);
            }
            {
                unsigned r;
                asm("v_cvt_pk_bf16_f32 %0, %1, %2" : "=v"(r) : "v"(y[16]), "v"(y[16]));
                yrow[16 * YPITCH] = (short)(r & 0xffffu);
            }

            __syncthreads();   // drains vmcnt(0): Ws landed; Ys visible

            // ---- MFMA: 5 M-tiles x 4 N-tiles x 2 K-slices ----
            #pragma unroll
            for (int ks = 0; ks < 2; ks++) {
                const int ko = ks * 32 + quad * 8;
                s8v bf[4], af[MT];
                #pragma unroll
                for (int nt = 0; nt < 4; nt++) {
                    int n = wave * 64 + nt * 16 + mn;
                    bf[nt] = *(const s8v*)(Ws + n * 64 + (ko ^ ((n & 7) << 3)));
                }
                #pragma unroll
                for (int mt = 0; mt < MT; mt++)
                    af[mt] = *(const s8v*)(Ys + (mt * 16 + mn) * YPITCH + ko);
                #pragma unroll
                for (int nt = 0; nt < 4; nt++) {
                    #pragma unroll
                    for (int mt = 0; mt < MT; mt++)
                        acc[mt][nt] = __builtin_amdgcn_mfma_f32_16x16x32_bf16(
                            af[mt], bf[nt], acc[mt][nt], 0, 0, 0);
                }
            }
            __syncthreads();   // before next k overwrites Ys/Ws
        }
    }

    // ---- epilogue: C/D layout col=lane&15, row=quad*4+reg ----
    #pragma unroll
    for (int mt = 0; mt < MT; mt++) {
        #pragma unroll
        for (int rg = 0; rg < 4; rg++) {
            int r = mt * 16 + quad * 4 + rg;
            if (r < MROWS) {
                #pragma unroll
                for (int nt = 0; nt < 4; nt++)
                    og[r * 256 + wave * 64 + nt * 16 + mn] = acc[mt][nt][rg];
            }
        }
    }
}

extern "C" void kernel_launch(void* const* d_in, const int* in_sizes, int n_in,
                              void* d_out, int out_size, void* d_ws, size_t ws_size,
                              hipStream_t stream) {
    const float* x    = (const float*)d_in[0];
    const float* W    = (const float*)d_in[1];
    const float* adj  = (const float*)d_in[2];
    const float* bias = (const float*)d_in[3];
    float* out = (float*)d_out;
    short* Wt  = (short*)d_ws;  // 3*256*256 bf16 = 393 KB

    hipLaunchKernelGGL(wt_transpose_kernel, dim3(48), dim3(256), 0, stream, W, Wt);
    hipLaunchKernelGGL(gconv_kernel, dim3(16384 / NB), dim3(256), 0, stream,
                       x, Wt, adj, bias, out);
}

// Round 2
// 825.931 us; speedup vs baseline: 1.2093x; 1.0029x over previous
//
#include <hip/hip_runtime.h>

typedef __attribute__((ext_vector_type(4))) float f4v;
typedef __attribute__((ext_vector_type(8))) short s8v;

#define YPITCH 72   // shorts; 144 B row pitch
#define NB 2        // batches per block
#define MROWS 34    // 2 x 17 rows
#define MT 3        // 48-row padded M tiles

static __device__ __forceinline__ short f2bf(float f) {
    unsigned u = __builtin_bit_cast(unsigned, f);
    unsigned r = (u + 0x7FFFu + ((u >> 16) & 1u)) >> 16;  // RNE
    return (short)r;
}

// W[3][256][256] (k,f,o) fp32  ->  Wt[3][256][256] (k,o,f) bf16, via LDS tile transpose
__global__ void wt_transpose_kernel(const float* __restrict__ W, short* __restrict__ Wt) {
    __shared__ short t[64][65];
    int k  = blockIdx.x >> 4;
    int r  = blockIdx.x & 15;
    int f0 = (r >> 2) << 6;
    int o0 = (r & 3) << 6;
    const float* Wk  = W  + k * 65536;
    short*       Wtk = Wt + k * 65536;
    #pragma unroll
    for (int e = 0; e < 16; e++) {
        int idx = e * 256 + threadIdx.x;
        int f = idx >> 6, o = idx & 63;
        t[f][o] = f2bf(Wk[(f0 + f) * 256 + o0 + o]);
    }
    __syncthreads();
    #pragma unroll
    for (int e = 0; e < 16; e++) {
        int idx = e * 256 + threadIdx.x;
        int o = idx >> 6, f = idx & 63;
        Wtk[(o0 + o) * 256 + f0 + f] = t[f][o];
    }
}

// PAR selects i-parity (wave>>1); K selects adjacency part. Fully unrolled const bounds.
template<int PAR, int K>
static __device__ __forceinline__ void aggregate(const float* __restrict__ adj,
                                                 const float xq[17], float y[9]) {
    constexpr int NI = PAR ? 8 : 9;
    #pragma unroll
    for (int t = 0; t < NI; t++) {
        const int i = 2 * t + PAR;
        float a;
        if (K == 0) {
            a = adj[i * 17 + i] * xq[i];
        } else if (K == 1) {
            a = 0.f;
            #pragma unroll
            for (int j = i + 1; j < 17; j++) a += adj[i * 17 + j] * xq[j];
        } else {
            a = 0.f;
            #pragma unroll
            for (int j = 0; j < i; j++) a += adj[i * 17 + j] * xq[j];
        }
        y[t] = a;
    }
}

template<int PAR>
static __device__ __forceinline__ void store_y(short* yb, const float y[9]) {
    constexpr int NI = PAR ? 8 : 9;
    #pragma unroll
    for (int t = 0; t < NI; t += 2) {
        unsigned r;
        float h = (t + 1 < NI) ? y[t + 1] : y[t];
        asm("v_cvt_pk_bf16_f32 %0, %1, %2" : "=v"(r) : "v"(y[t]), "v"(h));
        yb[(2 * t + PAR) * YPITCH] = (short)(r & 0xffffu);
        if (t + 1 < NI) yb[(2 * (t + 1) + PAR) * YPITCH] = (short)(r >> 16);
    }
}

// NB=2 batches/block, 4 waves. Wave w: agg batch (w&1), i-parity (w>>1); MFMA N-quarter w.
// W fragments read direct from L2 (no LDS staging, no vmcnt drain at barriers).
// Ys double-buffered -> ONE raw barrier per k-step.
// MFMA operands swapped (A=W rows -> D rows = output cols) -> float4 epilogue stores.
__global__ __launch_bounds__(256, 4) void gconv_kernel(
        const float* __restrict__ x, const short* __restrict__ Wt,
        const float* __restrict__ adj, const float* __restrict__ bias,
        float* __restrict__ out) {
    __shared__ __align__(16) short Ys[2][48 * YPITCH];   // 2 x 6912 B = 13824 B

    const int tid  = threadIdx.x;
    const int wave = tid >> 6;
    const int lane = tid & 63;
    const int mn   = lane & 15;
    const int quad = lane >> 4;
    const int bb   = wave & 1;     // batch for aggregation
    const int par  = wave >> 1;    // i-parity for aggregation
    const int f    = lane;         // f-column within 64-wide chunk

    const float* xg = x   + (size_t)blockIdx.x * (NB * 17 * 256);
    float*       og = out + (size_t)blockIdx.x * (NB * 17 * 256);

    f4v acc[MT][4];
    #pragma unroll
    for (int nt = 0; nt < 4; nt++) {
        f4v bv = *(const f4v*)(bias + wave * 64 + nt * 16 + quad * 4);
        #pragma unroll
        for (int mt = 0; mt < MT; mt++) acc[mt][nt] = bv;
    }

    int buf = 0;
    for (int fc0 = 0; fc0 < 256; fc0 += 64) {
        float xq[17];
        #pragma unroll
        for (int j = 0; j < 17; j++) xq[j] = xg[(bb * 17 + j) * 256 + fc0 + f];

        #pragma unroll
        for (int k = 0; k < 3; k++) {
            // ---- W fragments: direct global->reg, issued before agg (L2 latency cover) ----
            const short* Wtk = Wt + k * 65536;
            s8v wf[2][4];
            #pragma unroll
            for (int ks = 0; ks < 2; ks++)
                #pragma unroll
                for (int nt = 0; nt < 4; nt++)
                    wf[ks][nt] = *(const s8v*)(Wtk + (wave * 64 + nt * 16 + mn) * 256
                                               + fc0 + ks * 32 + quad * 8);

            // ---- aggregation (i-parity split across wave pairs), fp32 regs ----
            float y[9];
            short* yb = &Ys[buf][(bb * 17) * YPITCH + f];
            if (par == 0) {
                if      (k == 0) aggregate<0, 0>(adj, xq, y);
                else if (k == 1) aggregate<0, 1>(adj, xq, y);
                else             aggregate<0, 2>(adj, xq, y);
                store_y<0>(yb, y);
            } else {
                if      (k == 0) aggregate<1, 0>(adj, xq, y);
                else if (k == 1) aggregate<1, 1>(adj, xq, y);
                else             aggregate<1, 2>(adj, xq, y);
                store_y<1>(yb, y);
            }

            // ---- one barrier per k-step: drain LDS writes only (no vmcnt drain) ----
            asm volatile("s_waitcnt lgkmcnt(0)" ::: "memory");
            __builtin_amdgcn_s_barrier();
            __builtin_amdgcn_sched_barrier(0);

            // ---- MFMA: A = W rows (o), B = Y rows (r) ----
            #pragma unroll
            for (int ks = 0; ks < 2; ks++) {
                const int ko = ks * 32 + quad * 8;
                s8v af[MT];
                #pragma unroll
                for (int mt = 0; mt < MT; mt++)
                    af[mt] = *(const s8v*)(&Ys[buf][(mt * 16 + mn) * YPITCH + ko]);
                #pragma unroll
                for (int nt = 0; nt < 4; nt++)
                    #pragma unroll
                    for (int mt = 0; mt < MT; mt++)
                        acc[mt][nt] = __builtin_amdgcn_mfma_f32_16x16x32_bf16(
                            wf[ks][nt], af[mt], acc[mt][nt], 0, 0, 0);
            }
            buf ^= 1;
            // rows 34..47 of Ys are never written: their garbage lands only in
            // acc columns (mn>=2 of mt=2) that the epilogue never stores.
        }
    }

    // ---- epilogue: D row = quad*4+rg = o (contiguous) -> one float4 store per tile ----
    #pragma unroll
    for (int mt = 0; mt < MT; mt++) {
        const int r = mt * 16 + mn;
        if (r < MROWS) {
            #pragma unroll
            for (int nt = 0; nt < 4; nt++)
                *(f4v*)(og + r * 256 + wave * 64 + nt * 16 + quad * 4) = acc[mt][nt];
        }
    }
}

extern "C" void kernel_launch(void* const* d_in, const int* in_sizes, int n_in,
                              void* d_out, int out_size, void* d_ws, size_t ws_size,
                              hipStream_t stream) {
    const float* x    = (const float*)d_in[0];
    const float* W    = (const float*)d_in[1];
    const float* adj  = (const float*)d_in[2];
    const float* bias = (const float*)d_in[3];
    float* out = (float*)d_out;
    short* Wt  = (short*)d_ws;  // 3*256*256 bf16 = 393 KB

    hipLaunchKernelGGL(wt_transpose_kernel, dim3(48), dim3(256), 0, stream, W, Wt);
    hipLaunchKernelGGL(gconv_kernel, dim3(16384 / NB), dim3(256), 0, stream,
                       x, Wt, adj, bias, out);
}

// Round 3
// 659.601 us; speedup vs baseline: 1.5143x; 1.2522x over previous
//
#include <hip/hip_runtime.h>

typedef __attribute__((ext_vector_type(4))) float f4v;
typedef __attribute__((ext_vector_type(8))) short s8v;

#define YPITCH 72   // shorts; 144 B row pitch
#define NB 8        // batches per block
#define MROWS 136   // 8 x 17 rows
#define MT 9        // padded to 144 rows

static __device__ __forceinline__ short f2bf(float f) {
    unsigned u = __builtin_bit_cast(unsigned, f);
    unsigned r = (u + 0x7FFFu + ((u >> 16) & 1u)) >> 16;  // RNE
    return (short)r;
}

// W[3][256][256] (k,f,o) fp32  ->  Wt[3][256][256] (k,o,f) bf16, via LDS tile transpose
__global__ void wt_transpose_kernel(const float* __restrict__ W, short* __restrict__ Wt) {
    __shared__ short t[64][65];
    int k  = blockIdx.x >> 4;
    int r  = blockIdx.x & 15;
    int f0 = (r >> 2) << 6;
    int o0 = (r & 3) << 6;
    const float* Wk  = W  + k * 65536;
    short*       Wtk = Wt + k * 65536;
    #pragma unroll
    for (int e = 0; e < 16; e++) {
        int idx = e * 256 + threadIdx.x;
        int f = idx >> 6, o = idx & 63;
        t[f][o] = f2bf(Wk[(f0 + f) * 256 + o0 + o]);
    }
    __syncthreads();
    #pragma unroll
    for (int e = 0; e < 16; e++) {
        int idx = e * 256 + threadIdx.x;
        int o = idx >> 6, f = idx & 63;
        Wtk[(o0 + o) * 256 + f0 + f] = t[f][o];
    }
}

// One adjacency-row dot product; i and K are compile-time constants after unroll.
template<int K>
static __device__ __forceinline__ float row_sum(const float* __restrict__ adj,
                                                const float xq[17], int i) {
    float a;
    if (K == 0) {
        a = adj[i * 17 + i] * xq[i];
    } else if (K == 1) {
        a = 0.f;
        #pragma unroll
        for (int j = i + 1; j < 17; j++) a += adj[i * 17 + j] * xq[j];
    } else {
        a = 0.f;
        #pragma unroll
        for (int j = 0; j < i; j++) a += adj[i * 17 + j] * xq[j];
    }
    return a;
}

template<int K>
static __device__ __forceinline__ void agg_store(const float* __restrict__ adj,
                                                 const float xq[17], short* yb) {
    // row pairs: compute -> cvt_pk -> store immediately (y stays transient, low VGPR)
    #pragma unroll
    for (int t = 0; t < 8; t++) {
        float a0 = row_sum<K>(adj, xq, 2 * t);
        float a1 = row_sum<K>(adj, xq, 2 * t + 1);
        unsigned r;
        asm("v_cvt_pk_bf16_f32 %0, %1, %2" : "=v"(r) : "v"(a0), "v"(a1));
        yb[(2 * t) * YPITCH]     = (short)(r & 0xffffu);
        yb[(2 * t + 1) * YPITCH] = (short)(r >> 16);
    }
    float a = row_sum<K>(adj, xq, 16);
    unsigned r;
    asm("v_cvt_pk_bf16_f32 %0, %1, %2" : "=v"(r) : "v"(a), "v"(a));
    yb[16 * YPITCH] = (short)(r & 0xffffu);
}

// 8-wave block, NB=8 batches: wave w aggregates batch w (17 joints), owns N-slice
// [w*32, w*32+32) for MFMA. W fragments direct from L2 (16 VGPR, prefetch before agg).
// Ys double-buffered, ONE lgkm-only barrier per k-step. Swapped MFMA operands ->
// contiguous float4 epilogue stores.
__global__ __launch_bounds__(512, 4) void gconv_kernel(
        const float* __restrict__ x, const short* __restrict__ Wt,
        const float* __restrict__ adj, const float* __restrict__ bias,
        float* __restrict__ out) {
    __shared__ __align__(16) short Ys[2][144 * YPITCH];   // 2 x 20736 B = 41472 B

    const int tid  = threadIdx.x;
    const int wave = tid >> 6;       // 0..7
    const int lane = tid & 63;
    const int mn   = lane & 15;
    const int quad = lane >> 4;
    const int bb   = wave;           // batch for aggregation
    const int f    = lane;           // f-column within 64-wide chunk

    const float* xg = x   + (size_t)blockIdx.x * (NB * 17 * 256);
    float*       og = out + (size_t)blockIdx.x * (NB * 17 * 256);

    // zero the pad rows 136..143 of both buffers (one-time; covered by first barrier)
    for (int idx = tid; idx < 8 * YPITCH; idx += 512) {
        Ys[0][MROWS * YPITCH + idx] = 0;
        Ys[1][MROWS * YPITCH + idx] = 0;
    }

    f4v acc[MT][2];
    #pragma unroll
    for (int nt = 0; nt < 2; nt++) {
        f4v bv = *(const f4v*)(bias + wave * 32 + nt * 16 + quad * 4);
        #pragma unroll
        for (int mt = 0; mt < MT; mt++) acc[mt][nt] = bv;
    }

    int buf = 0;
    for (int fc0 = 0; fc0 < 256; fc0 += 64) {
        float xq[17];
        #pragma unroll
        for (int j = 0; j < 17; j++) xq[j] = xg[(bb * 17 + j) * 256 + fc0 + f];

        #pragma unroll
        for (int k = 0; k < 3; k++) {
            // ---- W fragments: global->reg from L2, issued before agg (latency cover) ----
            const short* Wtk = Wt + k * 65536;
            s8v wf[2][2];
            #pragma unroll
            for (int ks = 0; ks < 2; ks++)
                #pragma unroll
                for (int nt = 0; nt < 2; nt++)
                    wf[ks][nt] = *(const s8v*)(Wtk + (wave * 32 + nt * 16 + mn) * 256
                                               + fc0 + ks * 32 + quad * 8);

            // ---- aggregation: batch bb, all 17 joints, fused cvt+store ----
            short* yb = &Ys[buf][(bb * 17) * YPITCH + f];
            if      (k == 0) agg_store<0>(adj, xq, yb);
            else if (k == 1) agg_store<1>(adj, xq, yb);
            else             agg_store<2>(adj, xq, yb);

            // ---- one barrier per k-step: drain LDS writes only (no vmcnt drain) ----
            asm volatile("s_waitcnt lgkmcnt(0)" ::: "memory");
            __builtin_amdgcn_s_barrier();
            __builtin_amdgcn_sched_barrier(0);

            // ---- MFMA: A = W rows (o), B = Y rows -> D rows are contiguous o ----
            #pragma unroll
            for (int ks = 0; ks < 2; ks++) {
                const int ko = ks * 32 + quad * 8;
                #pragma unroll
                for (int mt = 0; mt < MT; mt++) {
                    s8v af = *(const s8v*)(&Ys[buf][(mt * 16 + mn) * YPITCH + ko]);
                    acc[mt][0] = __builtin_amdgcn_mfma_f32_16x16x32_bf16(
                        wf[ks][0], af, acc[mt][0], 0, 0, 0);
                    acc[mt][1] = __builtin_amdgcn_mfma_f32_16x16x32_bf16(
                        wf[ks][1], af, acc[mt][1], 0, 0, 0);
                }
            }
            buf ^= 1;
        }
    }

    // ---- epilogue: D row = quad*4+rg = o (contiguous) -> one float4 store per tile ----
    #pragma unroll
    for (int mt = 0; mt < MT; mt++) {
        const int r = mt * 16 + mn;
        if (r < MROWS) {
            #pragma unroll
            for (int nt = 0; nt < 2; nt++)
                *(f4v*)(og + r * 256 + wave * 32 + nt * 16 + quad * 4) = acc[mt][nt];
        }
    }
}

extern "C" void kernel_launch(void* const* d_in, const int* in_sizes, int n_in,
                              void* d_out, int out_size, void* d_ws, size_t ws_size,
                              hipStream_t stream) {
    const float* x    = (const float*)d_in[0];
    const float* W    = (const float*)d_in[1];
    const float* adj  = (const float*)d_in[2];
    const float* bias = (const float*)d_in[3];
    float* out = (float*)d_out;
    short* Wt  = (short*)d_ws;  // 3*256*256 bf16 = 393 KB

    hipLaunchKernelGGL(wt_transpose_kernel, dim3(48), dim3(256), 0, stream, W, Wt);
    hipLaunchKernelGGL(gconv_kernel, dim3(16384 / NB), dim3(512), 0, stream,
                       x, Wt, adj, bias, out);
}